// Round 6
// baseline (235.018 us; speedup 1.0000x reference)
//
#include <hip/hip_runtime.h>

// IBNModel: graph-coupled bidirectional GRU + decoder. All fp32 in/out.
// B=16, H=64, N=512, C=3, E=128, D=32, L_OUT=12, LAYERS=2.
//
//  K1 prep : softmax(relu(E1 E2^T)) -> fp16 transposed AfT/AbT; adj -> adjT;
//            x -> xT16[b,t][c][n] fp16; Uf/Wf/bf -> fp16 frag table ufrag;
//            Wb/bb -> wbfrag.
//  K2 msg  : MFMA GEMM, A-frags direct from xT16. Rows packed 12 halves:
//            [x(3), x@adj(3), x@Af(3), 1, 0, 0].
//  K3 rec  : MFMA recurrence with TWO-COLUMN-GROUP SOFTWARE PIPELINE:
//            block = 32 cols (groups alpha=0..15, beta=16..31), grid 256,
//            8 waves. Each barrier interval runs P1(X,t) + P2(Y,t') — two
//            independent chains per wave (ILP across the barrier-bound
//            critical path). Barriers per step-per-col halved vs round 5.

typedef _Float16 half8_t __attribute__((ext_vector_type(8)));
typedef float float4_t __attribute__((ext_vector_type(4)));

#define PIN(x) asm volatile("" : "+v"(x))

__device__ __forceinline__ float sigmoidf_(float x) {
  return __builtin_amdgcn_rcpf(1.f + __expf(-x));
}
__device__ __forceinline__ float tanhf_(float x) {
  return fmaf(-2.f, __builtin_amdgcn_rcpf(__expf(2.f * x) + 1.f), 1.f);
}

// ---------------- K1: prep --------------------------------------------------
__global__ __launch_bounds__(256) void prep_kernel(
    const float* __restrict__ E1f, const float* __restrict__ E2f,
    const float* __restrict__ E1b, const float* __restrict__ E2b,
    const float* __restrict__ adj, const float* __restrict__ x,
    const float* __restrict__ Wf, const float* __restrict__ Uf,
    const float* __restrict__ bf, const float* __restrict__ Wb,
    const float* __restrict__ bb, _Float16* __restrict__ adjT,
    _Float16* __restrict__ AfT, _Float16* __restrict__ AbT,
    _Float16* __restrict__ xT16, _Float16* __restrict__ ufrag,
    _Float16* __restrict__ wbfrag) {
  int bid = blockIdx.x;
  int tid = threadIdx.x;
  if (bid >= 1288) {  // xT16: 1024 blocks, one per (b,t)
    int bid2 = bid - 1288;
    int b = bid2 >> 6, t = bid2 & 63;
    const float2* xp = (const float2*)(x + (size_t)(b * 64 + t) * 1536);
    float2 f0 = xp[tid * 3], f1 = xp[tid * 3 + 1], f2 = xp[tid * 3 + 2];
    _Float16* dst = xT16 + (size_t)(b * 64 + t) * 1536;
    int n0_ = tid * 2;
    dst[n0_] = (_Float16)f0.x;
    dst[512 + n0_] = (_Float16)f0.y;
    dst[1024 + n0_] = (_Float16)f1.x;
    dst[n0_ + 1] = (_Float16)f1.y;
    dst[512 + n0_ + 1] = (_Float16)f2.x;
    dst[1024 + n0_ + 1] = (_Float16)f2.y;
    return;
  }
  if (bid >= 1272) {  // wbfrag: 16 regions r2 = og*2 + (gi-1)
    int r2 = bid - 1272;
    int gi = 1 + (r2 & 1);
    int og = r2 >> 1;
    for (int e = tid; e < 512; e += 256) {
      int lane = e >> 3, j = e & 7;
      int o = og * 16 + (lane & 15);
      int q = (lane >> 4) * 8 + j;
      float v = (q < 9) ? Wb[gi * 1152 + o * 9 + q]
                        : (q == 9 ? bb[gi * 128 + o] : 0.f);
      wbfrag[r2 * 512 + e] = (_Float16)v;
    }
    return;
  }
  if (bid >= 1152) {  // ufrag: 120 regions r = (og*3+gi)*5+kb, og 0..7
    int r = bid - 1152;
    int kb = r % 5;
    int gi = (r / 5) % 3;
    int og = r / 15;
    for (int e = tid; e < 512; e += 256) {
      int lane = e >> 3, j = e & 7;
      int o = og * 16 + (lane & 15);
      int q4 = lane >> 4;
      float v;
      if (kb < 4) {
        v = Uf[gi * 16384 + o * 128 + kb * 32 + q4 * 8 + j];
      } else {
        int q = q4 * 8 + j;
        v = (q < 9) ? Wf[gi * 1152 + o * 9 + q]
                    : (q == 9 ? bf[gi * 128 + o] : 0.f);
      }
      ufrag[r * 512 + e] = (_Float16)v;
    }
    return;
  }
  if (bid >= 1024) {  // adj -> adjT fp16 (transpose)
    int base = (bid - 1024) * 4;
    for (int r = 0; r < 4; ++r) {
      int row = base + r;
      float v0 = adj[row * 512 + tid];
      float v1 = adj[row * 512 + tid + 256];
      adjT[(size_t)tid * 512 + row] = (_Float16)v0;
      adjT[(size_t)(tid + 256) * 512 + row] = (_Float16)v1;
    }
    return;
  }
  int which = bid >> 9;
  int row = bid & 511;
  const float* E1 = which ? E1b : E1f;
  const float* E2 = which ? E2b : E2f;
  _Float16* A = which ? AbT : AfT;
  __shared__ float e1s[32];
  __shared__ float red[256];
  if (tid < 32) e1s[tid] = E1[row * 32 + tid];
  __syncthreads();
  float s[2];
#pragma unroll
  for (int h = 0; h < 2; ++h) {
    int m = tid + h * 256;
    const float4* e2 = (const float4*)(E2 + m * 32);
    float acc = 0.f;
#pragma unroll
    for (int d4 = 0; d4 < 8; ++d4) {
      float4 v = e2[d4];
      acc = fmaf(v.x, e1s[d4 * 4 + 0], acc);
      acc = fmaf(v.y, e1s[d4 * 4 + 1], acc);
      acc = fmaf(v.z, e1s[d4 * 4 + 2], acc);
      acc = fmaf(v.w, e1s[d4 * 4 + 3], acc);
    }
    s[h] = fmaxf(acc, 0.f);
  }
  red[tid] = fmaxf(s[0], s[1]);
  __syncthreads();
  for (int off = 128; off > 0; off >>= 1) {
    if (tid < off) red[tid] = fmaxf(red[tid], red[tid + off]);
    __syncthreads();
  }
  float mx = red[0];
  __syncthreads();
  float e0 = __expf(s[0] - mx), e1v = __expf(s[1] - mx);
  red[tid] = e0 + e1v;
  __syncthreads();
  for (int off = 128; off > 0; off >>= 1) {
    if (tid < off) red[tid] += red[tid + off];
    __syncthreads();
  }
  float inv = __builtin_amdgcn_rcpf(red[0]);
  A[(size_t)tid * 512 + row] = (_Float16)(e0 * inv);
  A[(size_t)(tid + 256) * 512 + row] = (_Float16)(e1v * inv);
}

// ---------------- K2: message GEMM (MFMA, direct A loads) -------------------
__global__ __launch_bounds__(256, 4) void msg_kernel(
    const _Float16* __restrict__ xT16, const _Float16* __restrict__ adjT,
    const _Float16* __restrict__ AfT, const _Float16* __restrict__ AbT,
    _Float16* __restrict__ msg16, _Float16* __restrict__ msgb16) {
  __shared__ __align__(8) _Float16 Sst[512 * 12];  // 12 KB
  int tid = threadIdx.x;
  int t = blockIdx.x >> 4;
  int n0g = (blockIdx.x & 15) * 32;
  int lane = tid & 63, og = tid >> 6;
  int l15 = lane & 15, q4 = lane >> 4, q0 = q4 * 8;
  int nt = og & 1, mat = og >> 1;
  bool is63 = (t == 63);
  bool doAb = is63 && (mat == 0);

  const _Float16* Bmat = mat ? AfT : adjT;
  int n = n0g + nt * 16 + l15;

  const float4_t zero4 = {0.f, 0.f, 0.f, 0.f};
  float4_t acc[3], accb[3];
#pragma unroll
  for (int mt = 0; mt < 3; ++mt) { acc[mt] = zero4; accb[mt] = zero4; }

  for (int kb = 0; kb < 16; ++kb) {
    half8_t b0 = *(const half8_t*)&Bmat[(size_t)n * 512 + kb * 32 + q0];
    half8_t b2;
    if (doAb) b2 = *(const half8_t*)&AbT[(size_t)n * 512 + kb * 32 + q0];
#pragma unroll
    for (int mt = 0; mt < 3; ++mt) {
      int m = mt * 16 + l15;
      int bm = (m * 21846) >> 16;
      int cm = m - bm * 3;
      half8_t a = *(const half8_t*)
          &xT16[((size_t)(bm * 64 + t) * 3 + cm) * 512 + kb * 32 + q0];
      acc[mt] = __builtin_amdgcn_mfma_f32_16x16x32_f16(a, b0, acc[mt], 0, 0, 0);
      if (doAb)
        accb[mt] = __builtin_amdgcn_mfma_f32_16x16x32_f16(a, b2, accb[mt], 0, 0, 0);
    }
  }

  for (int i = tid; i < 512; i += 256) {
    int tb = i >> 5, nl = i & 31;
    int nn = n0g + nl;
    _Float16* row = &Sst[i * 12];
#pragma unroll
    for (int c = 0; c < 3; ++c)
      row[c] = xT16[((size_t)(tb * 64 + t) * 3 + c) * 512 + nn];
    row[9] = (_Float16)1.f;
    row[10] = (_Float16)0.f;
    row[11] = (_Float16)0.f;
  }
#pragma unroll
  for (int mt = 0; mt < 3; ++mt)
#pragma unroll
    for (int r = 0; r < 4; ++r) {
      int m = mt * 16 + q4 * 4 + r;
      int tb = (m * 21846) >> 16;
      int c = m - tb * 3;
      Sst[((size_t)tb * 32 + nt * 16 + l15) * 12 + 3 + mat * 3 + c] =
          (_Float16)acc[mt][r];
    }
  __syncthreads();
  for (int i = tid; i < 512; i += 256) {
    int tb = i >> 5, nl = i & 31;
    const uint2* s = (const uint2*)&Sst[i * 12];
    uint2* dst = (uint2*)&msg16[((size_t)(t * 16 + tb) * 512 + n0g + nl) * 12];
    dst[0] = s[0]; dst[1] = s[1]; dst[2] = s[2];
  }
  if (is63) {
    __syncthreads();
    if (mat == 0) {
#pragma unroll
      for (int mt = 0; mt < 3; ++mt)
#pragma unroll
        for (int r = 0; r < 4; ++r) {
          int m = mt * 16 + q4 * 4 + r;
          int tb = (m * 21846) >> 16;
          int c = m - tb * 3;
          Sst[((size_t)tb * 32 + nt * 16 + l15) * 12 + 6 + c] = (_Float16)accb[mt][r];
        }
    }
    __syncthreads();
    for (int i = tid; i < 512; i += 256) {
      int tb = i >> 5, nl = i & 31;
      const uint2* s = (const uint2*)&Sst[i * 12];
      uint2* dst = (uint2*)&msgb16[((size_t)tb * 512 + n0g + nl) * 12];
      dst[0] = s[0]; dst[1] = s[1]; dst[2] = s[2];
    }
  }
}

// ---------------- K3: MFMA recurrence, two-group pipeline -------------------
// grid 256 = b(16) x ntile(16, 32 cols); 512 thr = 8 waves, 1 block/CU.
// Wave og owns rows og*16..+15. Groups: alpha = cols 0-15, beta = 16-31.
// Interval: P1(X,t) [r,u gates + g-msg-init + rc write] in parallel with
// P2(Y,t') [g gate over rc + c update] — two independent chains per wave.
__global__ __launch_bounds__(512, 2) void rec_kernel(
    const _Float16* __restrict__ msg16, const _Float16* __restrict__ msgb16,
    const _Float16* __restrict__ ufrag, const _Float16* __restrict__ wbfrag,
    const float* __restrict__ dec_w, const float* __restrict__ dec_b,
    const float* __restrict__ out_w, const float* __restrict__ out_b,
    float* __restrict__ out) {
  __shared__ __align__(16) _Float16 Cbuf[2][2048];  // 8 KB
  __shared__ __align__(16) _Float16 Gbuf[2][2048];  // 8 KB
  __shared__ float hf_lds[128 * 32];                // 16 KB
  __shared__ float hb_lds[128 * 32];                // 16 KB
  __shared__ float hdec_lds[12 * 32];
  int tid = threadIdx.x, bid = blockIdx.x;
  int b = bid >> 4;
  int n0 = (bid & 15) * 32;
  int lane = tid & 63, og = tid >> 6;
  int l15 = lane & 15, q4 = lane >> 4;

  // persistent A frags, pinned (AGPR/VGPR resident)
  half8_t afrag[3][5];
#pragma unroll
  for (int gi = 0; gi < 3; ++gi)
#pragma unroll
    for (int kb = 0; kb < 5; ++kb) {
      afrag[gi][kb] = *(const half8_t*)
          &ufrag[(size_t)(((og * 3 + gi) * 5 + kb) * 512) + lane * 8];
      PIN(afrag[gi][kb]);
    }

  {
    uint4 z; z.x = z.y = z.z = z.w = 0;
    ((uint4*)&Cbuf[0][0])[tid] = z;  // 512 * 16B = both groups
  }

  const float4_t zero4 = {0.f, 0.f, 0.f, 0.f};
  union H4U { _Float16 h[4]; unsigned long long u; };
  union U16 { uint4 u4; half8_t h8; };
  unsigned odd = q4 & 1;
  const size_t tstride = (size_t)16 * 512 * 24;
  const char* mrow[2];
  mrow[0] = (const char*)msg16 + ((size_t)(b * 512 + n0 + l15)) * 24;
  mrow[1] = mrow[0] + 16 * 24;

  float cr[2][4] = {{0.f, 0.f, 0.f, 0.f}, {0.f, 0.f, 0.f, 0.f}};
  float4_t accu[2], accg[2];
  uint4 pf_lo[2];
  uint2 pf_hi[2];
  // prologue prefetch t=0 for both groups
#pragma unroll
  for (int g = 0; g < 2; ++g) {
    pf_lo[g] = *(const uint4*)mrow[g];
    pf_hi[g] = *(const uint2*)(mrow[g] + 16);
  }

  int kb_w = og >> 1;
  int lane_w = ((og & 1) * 2 + (q4 >> 1)) * 16 + l15;
  int j0 = (q4 & 1) * 4;

  auto P1 = [&](int g, int tn) {
    U16 bu;
    bu.u4.x = odd ? pf_hi[g].x : pf_lo[g].x;
    bu.u4.y = odd ? pf_hi[g].y : pf_lo[g].y;
    bu.u4.z = odd ? 0u : pf_lo[g].z;
    bu.u4.w = odd ? 0u : pf_lo[g].w;
    half8_t bm = bu.h8;
    half8_t cf[4];
#pragma unroll
    for (int kb = 0; kb < 4; ++kb)
      cf[kb] = *(const half8_t*)&Cbuf[g][(kb * 64 + lane) * 8];
    float4_t accr = zero4;
    float4_t au = zero4;
#pragma unroll
    for (int kb = 0; kb < 4; ++kb) {
      accr = __builtin_amdgcn_mfma_f32_16x16x32_f16(afrag[0][kb], cf[kb], accr, 0, 0, 0);
      au = __builtin_amdgcn_mfma_f32_16x16x32_f16(afrag[1][kb], cf[kb], au, 0, 0, 0);
    }
    accr = __builtin_amdgcn_mfma_f32_16x16x32_f16(afrag[0][4], bm, accr, 0, 0, 0);
    accu[g] = __builtin_amdgcn_mfma_f32_16x16x32_f16(afrag[1][4], bm, au, 0, 0, 0);
    accg[g] = __builtin_amdgcn_mfma_f32_16x16x32_f16(afrag[2][4], bm, zero4, 0, 0, 0);
    // prefetch next step for this group
    const char* p = mrow[g] + (size_t)tn * tstride;
    pf_lo[g] = *(const uint4*)p;
    pf_hi[g] = *(const uint2*)(p + 16);
    H4U v;
#pragma unroll
    for (int r = 0; r < 4; ++r)
      v.h[r] = (_Float16)(sigmoidf_(accr[r]) * cr[g][r]);
    *(unsigned long long*)&Gbuf[g][(kb_w * 64 + lane_w) * 8 + j0] = v.u;
  };

  auto P2 = [&](int g) {
    half8_t gf[4];
#pragma unroll
    for (int kb = 0; kb < 4; ++kb)
      gf[kb] = *(const half8_t*)&Gbuf[g][(kb * 64 + lane) * 8];
    float4_t ag = accg[g];
#pragma unroll
    for (int kb = 0; kb < 4; ++kb)
      ag = __builtin_amdgcn_mfma_f32_16x16x32_f16(afrag[2][kb], gf[kb], ag, 0, 0, 0);
    H4U v;
#pragma unroll
    for (int r = 0; r < 4; ++r) {
      float uu = sigmoidf_(accu[g][r]);
      float gg = tanhf_(ag[r]);
      float cn = fmaf(uu, cr[g][r] - gg, gg);  // u*c + (1-u)*g
      cr[g][r] = cn;
      v.h[r] = (_Float16)cn;
    }
    *(unsigned long long*)&Cbuf[g][(kb_w * 64 + lane_w) * 8 + j0] = v.u;
  };

  __syncthreads();
  P1(0, 1);  // alpha t=0 (prefetch alpha t=1)
  __syncthreads();
  for (int t = 0; t < 63; ++t) {
    P1(1, t + 1);  // beta t (prefetch beta t+1)
    P2(0);         // alpha t
    __syncthreads();
    int tn2 = (t < 61) ? t + 2 : 63;
    P1(0, tn2);    // alpha t+1 (prefetch alpha t+2)
    P2(1);         // beta t
    __syncthreads();
  }
  P1(1, 63);  // beta t=63
  P2(0);      // alpha t=63
  __syncthreads();
  P2(1);      // beta t=63

  // backward cell at t=63, c0=0: h_back = (1-sig(pre_u))*tanh(pre_g)
  {
    half8_t au_f = *(const half8_t*)&wbfrag[(size_t)((og * 2 + 0) * 512) + lane * 8];
    half8_t ag_f = *(const half8_t*)&wbfrag[(size_t)((og * 2 + 1) * 512) + lane * 8];
#pragma unroll
    for (int g = 0; g < 2; ++g) {
      const char* p = (const char*)msgb16 +
                      ((size_t)(b * 512 + n0 + g * 16 + l15)) * 24;
      uint4 lo = *(const uint4*)p;
      uint2 hi = *(const uint2*)(p + 16);
      U16 bu;
      bu.u4.x = odd ? hi.x : lo.x;
      bu.u4.y = odd ? hi.y : lo.y;
      bu.u4.z = odd ? 0u : lo.z;
      bu.u4.w = odd ? 0u : lo.w;
      float4_t au = __builtin_amdgcn_mfma_f32_16x16x32_f16(au_f, bu.h8, zero4, 0, 0, 0);
      float4_t ag = __builtin_amdgcn_mfma_f32_16x16x32_f16(ag_f, bu.h8, zero4, 0, 0, 0);
#pragma unroll
      for (int r = 0; r < 4; ++r) {
        int row = og * 16 + q4 * 4 + r;
        float uu = sigmoidf_(au[r]);
        float gg = tanhf_(ag[r]);
        hb_lds[row * 32 + g * 16 + l15] = (1.f - uu) * gg;
        hf_lds[row * 32 + g * 16 + l15] = cr[g][r];
      }
    }
  }
  __syncthreads();

  // decoder
  if (tid < 384) {
    int i = tid >> 5, cc = tid & 31;
    const float* dwa = dec_w + (size_t)i * 512;
    const float* dwb = dwa + 256;
    float hd = dec_b[i];
    for (int e = 0; e < 128; ++e) {
      hd = fmaf(dwa[e] + dwb[e], hf_lds[e * 32 + cc], hd);
      hd = fmaf(dwa[128 + e] + dwb[128 + e], hb_lds[e * 32 + cc], hd);
    }
    hdec_lds[i * 32 + cc] = hd;
  }
  __syncthreads();
  if (tid < 384) {
    int o = tid >> 5, cc = tid & 31;
    float v = out_b[o];
#pragma unroll
    for (int i = 0; i < 12; ++i) v = fmaf(out_w[o * 12 + i], hdec_lds[i * 32 + cc], v);
    out[((size_t)(b * 12 + o)) * 512 + n0 + cc] = v;
  }
}

extern "C" void kernel_launch(void* const* d_in, const int* in_sizes, int n_in,
                              void* d_out, int out_size, void* d_ws, size_t ws_size,
                              hipStream_t stream) {
  (void)in_sizes; (void)n_in; (void)out_size; (void)ws_size;
  const float* x     = (const float*)d_in[0];
  const float* adj   = (const float*)d_in[1];
  const float* Wf    = (const float*)d_in[2];
  const float* Uf    = (const float*)d_in[3];
  const float* bf    = (const float*)d_in[4];
  const float* E1f   = (const float*)d_in[5];
  const float* E2f   = (const float*)d_in[6];
  const float* Wb    = (const float*)d_in[7];
  const float* bb    = (const float*)d_in[9];
  const float* E1b   = (const float*)d_in[10];
  const float* E2b   = (const float*)d_in[11];
  const float* dec_w = (const float*)d_in[12];
  const float* dec_b = (const float*)d_in[13];
  const float* out_w = (const float*)d_in[14];
  const float* out_b = (const float*)d_in[15];

  _Float16* h      = (_Float16*)d_ws;
  _Float16* adjT   = h;                        //   262144
  _Float16* AfT    = h + 262144;               //   262144
  _Float16* AbT    = h + 524288;               //   262144
  _Float16* xT16   = h + 786432;               //  1572864
  _Float16* ufrag  = h + 2359296;              //    61440
  _Float16* wbfrag = h + 2420736;              //     8192
  _Float16* msg16  = h + 2428928;              //  6291456 (rows of 12 halves)
  _Float16* msgb16 = h + 8720384;              //    98304

  prep_kernel<<<2312, 256, 0, stream>>>(E1f, E2f, E1b, E2b, adj, x, Wf, Uf, bf,
                                        Wb, bb, adjT, AfT, AbT, xT16, ufrag, wbfrag);
  msg_kernel<<<1024, 256, 0, stream>>>(xT16, adjT, AfT, AbT, msg16, msgb16);
  rec_kernel<<<256, 512, 0, stream>>>(msg16, msgb16, ufrag, wbfrag,
                                      dec_w, dec_b, out_w, out_b, (float*)d_out);
}

// Round 8
// 203.027 us; speedup vs baseline: 1.1576x; 1.1576x over previous
//
#include <hip/hip_runtime.h>

// IBNModel: graph-coupled bidirectional GRU + decoder. All fp32 in/out.
// B=16, H=64, N=512, C=3, E=128, D=32, L_OUT=12, LAYERS=2.
//
//  K1 prep : softmax(relu(E1 E2^T)) -> fp16 transposed AfT/AbT; adj -> adjT;
//            Uf/Wf/bf -> fp16 frag table ufrag PRE-SCALED by -log2e (r,u) /
//            +2log2e (g) so activations need no mul; Wb/bb -> wbfrag (same).
//  K2 msg  : MFMA GEMM (x staged in XOR-swizzled LDS), writes msgF in the
//            EXACT B-fragment layout rec consumes: [slice=(b,ntile)][t]
//            [lane32][8 halves] -> rec's per-step load is ONE b128.
//  K3 rec  : R5 shape (16 cols/block, grid 512, 8 waves, 2 blocks/CU,
//            2 barriers/step), 15 pinned A-frags, exp2-based activations,
//            pkrtz packing, single-load msg stream.

typedef _Float16 half8_t __attribute__((ext_vector_type(8)));
typedef __fp16 fp16x2_t __attribute__((ext_vector_type(2)));
typedef float float4_t __attribute__((ext_vector_type(4)));

#define PIN(x) asm volatile("" : "+v"(x))

__device__ __forceinline__ float exp2_(float x) { return __builtin_amdgcn_exp2f(x); }
__device__ __forceinline__ float rcp_(float x) { return __builtin_amdgcn_rcpf(x); }

// ---------------- K1: prep --------------------------------------------------
__global__ __launch_bounds__(256) void prep_kernel(
    const float* __restrict__ E1f, const float* __restrict__ E2f,
    const float* __restrict__ E1b, const float* __restrict__ E2b,
    const float* __restrict__ adj, const float* __restrict__ Wf,
    const float* __restrict__ Uf, const float* __restrict__ bf,
    const float* __restrict__ Wb, const float* __restrict__ bb,
    _Float16* __restrict__ adjT, _Float16* __restrict__ AfT,
    _Float16* __restrict__ AbT, _Float16* __restrict__ ufrag,
    _Float16* __restrict__ wbfrag) {
  int bid = blockIdx.x;
  int tid = threadIdx.x;
  if (bid >= 1272) {  // wbfrag: 16 regions r2 = og*2 + (gi-1), pre-scaled
    int r2 = bid - 1272;
    int gi = 1 + (r2 & 1);
    int og = r2 >> 1;
    float scl = (gi == 2) ? 2.8853902f : -1.4426950f;
    for (int e = tid; e < 512; e += 256) {
      int lane = e >> 3, j = e & 7;
      int o = og * 16 + (lane & 15);
      int q = (lane >> 4) * 8 + j;
      float v = (q < 9) ? Wb[gi * 1152 + o * 9 + q]
                        : (q == 9 ? bb[gi * 128 + o] : 0.f);
      wbfrag[r2 * 512 + e] = (_Float16)(v * scl);
    }
    return;
  }
  if (bid >= 1152) {  // ufrag: 120 regions r = (og*3+gi)*5+kb, pre-scaled
    int r = bid - 1152;
    int kb = r % 5;
    int gi = (r / 5) % 3;
    int og = r / 15;
    float scl = (gi == 2) ? 2.8853902f : -1.4426950f;
    for (int e = tid; e < 512; e += 256) {
      int lane = e >> 3, j = e & 7;
      int o = og * 16 + (lane & 15);
      int q4 = lane >> 4;
      float v;
      if (kb < 4) {
        v = Uf[gi * 16384 + o * 128 + kb * 32 + q4 * 8 + j];
      } else {
        int q = q4 * 8 + j;
        v = (q < 9) ? Wf[gi * 1152 + o * 9 + q]
                    : (q == 9 ? bf[gi * 128 + o] : 0.f);
      }
      ufrag[r * 512 + e] = (_Float16)(v * scl);
    }
    return;
  }
  if (bid >= 1024) {  // adj -> adjT fp16 (transpose)
    int base = (bid - 1024) * 4;
    for (int r = 0; r < 4; ++r) {
      int row = base + r;
      float v0 = adj[row * 512 + tid];
      float v1 = adj[row * 512 + tid + 256];
      adjT[(size_t)tid * 512 + row] = (_Float16)v0;
      adjT[(size_t)(tid + 256) * 512 + row] = (_Float16)v1;
    }
    return;
  }
  int which = bid >> 9;
  int row = bid & 511;
  const float* E1 = which ? E1b : E1f;
  const float* E2 = which ? E2b : E2f;
  _Float16* A = which ? AbT : AfT;
  __shared__ float e1s[32];
  __shared__ float red[256];
  if (tid < 32) e1s[tid] = E1[row * 32 + tid];
  __syncthreads();
  float s[2];
#pragma unroll
  for (int h = 0; h < 2; ++h) {
    int m = tid + h * 256;
    const float4* e2 = (const float4*)(E2 + m * 32);
    float acc = 0.f;
#pragma unroll
    for (int d4 = 0; d4 < 8; ++d4) {
      float4 v = e2[d4];
      acc = fmaf(v.x, e1s[d4 * 4 + 0], acc);
      acc = fmaf(v.y, e1s[d4 * 4 + 1], acc);
      acc = fmaf(v.z, e1s[d4 * 4 + 2], acc);
      acc = fmaf(v.w, e1s[d4 * 4 + 3], acc);
    }
    s[h] = fmaxf(acc, 0.f);
  }
  red[tid] = fmaxf(s[0], s[1]);
  __syncthreads();
  for (int off = 128; off > 0; off >>= 1) {
    if (tid < off) red[tid] = fmaxf(red[tid], red[tid + off]);
    __syncthreads();
  }
  float mx = red[0];
  __syncthreads();
  float e0 = __expf(s[0] - mx), e1v = __expf(s[1] - mx);
  red[tid] = e0 + e1v;
  __syncthreads();
  for (int off = 128; off > 0; off >>= 1) {
    if (tid < off) red[tid] += red[tid + off];
    __syncthreads();
  }
  float inv = rcp_(red[0]);
  A[(size_t)tid * 512 + row] = (_Float16)(e0 * inv);
  A[(size_t)(tid + 256) * 512 + row] = (_Float16)(e1v * inv);
}

// ---------------- K2: message GEMM -> fragment-layout output ----------------
// grid 512 = t(64) x nc(8, 64 cols); 256 thr = 4 waves (og = local n16 tile),
// 2 blocks/CU (80 KB LDS). Output msgF[slice=(b*32+gnt)][t][lane32][8]:
//   lane32 = q4'(0,1)*16 + col: q4'=0 halves j=0..7 = rows [x0,x1,x2,
//   xa0,xa1,xa2,xf0,xf1]; q4'=1: j0=xf2, j1=1.0, j2..7=0.
__global__ __launch_bounds__(256, 2) void msg_kernel(
    const float* __restrict__ x, const _Float16* __restrict__ adjT,
    const _Float16* __restrict__ AfT, const _Float16* __restrict__ AbT,
    _Float16* __restrict__ msgF, _Float16* __restrict__ msgbF) {
  __shared__ __align__(16) _Float16 Alds[48 * 512];        // 48 KB
  __shared__ __align__(16) _Float16 Sst[16 * 4 * 32 * 8];  // 32 KB
  int tid = threadIdx.x;
  int t = blockIdx.x >> 3;
  int n0g = (blockIdx.x & 7) * 64;
  int g4 = (blockIdx.x & 7) * 4;
  int lane = tid & 63, og = tid >> 6;
  int l15 = lane & 15, q4 = lane >> 4, q0 = q4 * 8;
  bool is63 = (t == 63);

  // stage x -> Alds[m=b*3+c][k=n], XOR-swizzled (coalesced float4 reads)
  {
    int b = tid >> 4, li = tid & 15;
    const float4* xb = (const float4*)(x + (size_t)(b * 64 + t) * 1536);
#pragma unroll
    for (int k = 0; k < 24; ++k) {
      float4 v = xb[k * 16 + li];
      int j0 = (k * 16 + li) * 4;
#pragma unroll
      for (int e = 0; e < 4; ++e) {
        int j = j0 + e;
        int n = (j * 21846) >> 16;  // exact j/3 for j<2048
        int c = j - n * 3;
        int m = b * 3 + c;
        float val = (e == 0) ? v.x : (e == 1) ? v.y : (e == 2) ? v.z : v.w;
        Alds[m * 512 + ((((n >> 3) ^ (m & 7)) << 3) | (n & 7))] = (_Float16)val;
      }
    }
  }
  __syncthreads();

  const float4_t zero4 = {0.f, 0.f, 0.f, 0.f};
  float4_t acc[3][2], accb[3];
#pragma unroll
  for (int mt = 0; mt < 3; ++mt) { acc[mt][0] = zero4; acc[mt][1] = zero4; accb[mt] = zero4; }

  int n = n0g + og * 16 + l15;
  for (int kb = 0; kb < 16; ++kb) {
    half8_t afr[3];
#pragma unroll
    for (int mt = 0; mt < 3; ++mt) {
      int m = mt * 16 + l15;
      afr[mt] = *(const half8_t*)&Alds[m * 512 + ((((kb * 4 + q4) ^ (m & 7)) << 3))];
    }
    half8_t b0 = *(const half8_t*)&adjT[(size_t)n * 512 + kb * 32 + q0];
    half8_t b1 = *(const half8_t*)&AfT[(size_t)n * 512 + kb * 32 + q0];
#pragma unroll
    for (int mt = 0; mt < 3; ++mt) {
      acc[mt][0] = __builtin_amdgcn_mfma_f32_16x16x32_f16(afr[mt], b0, acc[mt][0], 0, 0, 0);
      acc[mt][1] = __builtin_amdgcn_mfma_f32_16x16x32_f16(afr[mt], b1, acc[mt][1], 0, 0, 0);
    }
    if (is63) {
      half8_t b2 = *(const half8_t*)&AbT[(size_t)n * 512 + kb * 32 + q0];
#pragma unroll
      for (int mt = 0; mt < 3; ++mt)
        accb[mt] = __builtin_amdgcn_mfma_f32_16x16x32_f16(afr[mt], b2, accb[mt], 0, 0, 0);
    }
  }

  // fill x rows (j0-2), bias (q4'=1 j1), zeros (q4'=1 j2-7)
  for (int u = tid; u < 1024; u += 256) {
    int tb = u >> 6, nt = (u >> 4) & 3, cl = u & 15;
    int nn = n0g + nt * 16 + cl;
    _Float16* r0 = &Sst[(((tb * 4 + nt) * 32) + cl) * 8];
    _Float16* r1 = r0 + 16 * 8;
#pragma unroll
    for (int c = 0; c < 3; ++c) {
      int m = tb * 3 + c;
      r0[c] = Alds[m * 512 + ((((nn >> 3) ^ (m & 7)) << 3) | (nn & 7))];
    }
    r1[1] = (_Float16)1.f;
#pragma unroll
    for (int z = 2; z < 8; ++z) r1[z] = (_Float16)0.f;
  }
  // MFMA results: C layout col=l15, row=q4*4+r. adj -> j=3+ch, Af -> j=6+ch
#pragma unroll
  for (int mt = 0; mt < 3; ++mt)
#pragma unroll
    for (int r = 0; r < 4; ++r) {
      int m = mt * 16 + q4 * 4 + r;
      int tb = (m * 21846) >> 16;
      int ch = m - tb * 3;
      _Float16* base = &Sst[((tb * 4 + og) * 32) * 8];
      base[(l15)*8 + 3 + ch] = (_Float16)acc[mt][0][r];
      if (ch < 2) base[(l15)*8 + 6 + ch] = (_Float16)acc[mt][1][r];
      else        base[(16 + l15) * 8 + 0] = (_Float16)acc[mt][1][r];
    }
  __syncthreads();
  // coalesced frag store: 64 slices x 32 lanes x 16 B
  for (int i = tid; i < 2048; i += 256) {
    int sl = i >> 5, lane32 = i & 31;
    int tb = sl >> 2, nt = sl & 3;
    ((uint4*)msgF)[((size_t)(tb * 32 + g4 + nt) * 64 + t) * 32 + lane32] =
        ((const uint4*)Sst)[i];
  }
  if (is63) {
    __syncthreads();
#pragma unroll
    for (int mt = 0; mt < 3; ++mt)
#pragma unroll
      for (int r = 0; r < 4; ++r) {
        int m = mt * 16 + q4 * 4 + r;
        int tb = (m * 21846) >> 16;
        int ch = m - tb * 3;
        _Float16* base = &Sst[((tb * 4 + og) * 32) * 8];
        if (ch < 2) base[(l15)*8 + 6 + ch] = (_Float16)accb[mt][r];
        else        base[(16 + l15) * 8 + 0] = (_Float16)accb[mt][r];
      }
    __syncthreads();
    for (int i = tid; i < 2048; i += 256) {
      int sl = i >> 5, lane32 = i & 31;
      int tb = sl >> 2, nt = sl & 3;
      ((uint4*)msgbF)[(size_t)(tb * 32 + g4 + nt) * 32 + lane32] =
          ((const uint4*)Sst)[i];
    }
  }
}

// ---------------- K3: MFMA recurrence + backward + decoder ------------------
// grid 512 = b(16) x ntile(32, 16 cols); 512 thr = 8 waves, 2 blocks/CU
// (4 waves/SIMD). Wave og owns rows og*16..+15; 15 pinned A-frags.
__global__ __launch_bounds__(512, 4) void rec_kernel(
    const _Float16* __restrict__ msgF, const _Float16* __restrict__ msgbF,
    const _Float16* __restrict__ ufrag, const _Float16* __restrict__ wbfrag,
    const float* __restrict__ dec_w, const float* __restrict__ dec_b,
    const float* __restrict__ out_w, const float* __restrict__ out_b,
    float* __restrict__ out) {
  __shared__ __align__(16) _Float16 Cbuf[2048];  // 4 KB
  __shared__ __align__(16) _Float16 Gbuf[2048];  // 4 KB
  __shared__ float hf_lds[128 * 16];
  __shared__ float hb_lds[128 * 16];
  __shared__ float hdec_lds[12 * 16];
  int tid = threadIdx.x, bid = blockIdx.x;
  int b = bid >> 5;
  int nt = bid & 31;
  int n0 = nt * 16;
  int lane = tid & 63, og = tid >> 6;
  int l15 = lane & 15, q4 = lane >> 4;

  half8_t afrag[3][5];
#pragma unroll
  for (int gi = 0; gi < 3; ++gi)
#pragma unroll
    for (int kb = 0; kb < 5; ++kb) {
      afrag[gi][kb] = *(const half8_t*)
          &ufrag[(size_t)(((og * 3 + gi) * 5 + kb) * 512) + lane * 8];
      PIN(afrag[gi][kb]);
    }

  if (tid < 256) {
    uint4 z; z.x = z.y = z.z = z.w = 0;
    ((uint4*)Cbuf)[tid] = z;
  }
  float cr[4] = {0.f, 0.f, 0.f, 0.f};

  const float4_t zero4 = {0.f, 0.f, 0.f, 0.f};
  union H4U { fp16x2_t h2[2]; unsigned long long u; };
  const _Float16* mp = msgF + (size_t)(b * 32 + nt) * 64 * 256 + (lane & 31) * 8;
  half8_t bm = *(const half8_t*)mp;

  int kb_w = og >> 1;
  int lane_w = ((og & 1) * 2 + (q4 >> 1)) * 16 + l15;
  int j0 = (q4 & 1) * 4;
  __syncthreads();

  for (int t = 0; t < 64; ++t) {
    mp += 256;
    half8_t bm_n = *(const half8_t*)mp;  // t=63 reads into msgbF region: unused

    half8_t cf[4];
#pragma unroll
    for (int kb = 0; kb < 4; ++kb)
      cf[kb] = *(const half8_t*)&Cbuf[(kb * 64 + lane) * 8];

    float4_t accr = zero4, accu = zero4;
#pragma unroll
    for (int kb = 0; kb < 4; ++kb) {
      accr = __builtin_amdgcn_mfma_f32_16x16x32_f16(afrag[0][kb], cf[kb], accr, 0, 0, 0);
      accu = __builtin_amdgcn_mfma_f32_16x16x32_f16(afrag[1][kb], cf[kb], accu, 0, 0, 0);
    }
    accr = __builtin_amdgcn_mfma_f32_16x16x32_f16(afrag[0][4], bm, accr, 0, 0, 0);
    accu = __builtin_amdgcn_mfma_f32_16x16x32_f16(afrag[1][4], bm, accu, 0, 0, 0);
    float4_t accg = __builtin_amdgcn_mfma_f32_16x16x32_f16(afrag[2][4], bm, zero4, 0, 0, 0);

    {  // r = rcp(1+exp2(accr)) [weights pre-scaled by -log2e]; rc -> Gbuf
      float rc0 = rcp_(1.f + exp2_(accr[0])) * cr[0];
      float rc1 = rcp_(1.f + exp2_(accr[1])) * cr[1];
      float rc2 = rcp_(1.f + exp2_(accr[2])) * cr[2];
      float rc3 = rcp_(1.f + exp2_(accr[3])) * cr[3];
      H4U v;
      v.h2[0] = __builtin_amdgcn_cvt_pkrtz(rc0, rc1);
      v.h2[1] = __builtin_amdgcn_cvt_pkrtz(rc2, rc3);
      *(unsigned long long*)&Gbuf[(kb_w * 64 + lane_w) * 8 + j0] = v.u;
    }
    __syncthreads();  // rc visible; Cbuf reads done

    half8_t gf[4];
#pragma unroll
    for (int kb = 0; kb < 4; ++kb)
      gf[kb] = *(const half8_t*)&Gbuf[(kb * 64 + lane) * 8];
#pragma unroll
    for (int kb = 0; kb < 4; ++kb)
      accg = __builtin_amdgcn_mfma_f32_16x16x32_f16(afrag[2][kb], gf[kb], accg, 0, 0, 0);

    {  // u = rcp(1+exp2(accu)); g = 1-2*rcp(1+exp2(accg)) [pre-scaled +2log2e]
      H4U v;
      float cn[4];
#pragma unroll
      for (int r = 0; r < 4; ++r) {
        float uu = rcp_(1.f + exp2_(accu[r]));
        float gg = fmaf(-2.f, rcp_(exp2_(accg[r]) + 1.f), 1.f);
        cn[r] = fmaf(uu, cr[r] - gg, gg);  // u*c + (1-u)*g
        cr[r] = cn[r];
      }
      v.h2[0] = __builtin_amdgcn_cvt_pkrtz(cn[0], cn[1]);
      v.h2[1] = __builtin_amdgcn_cvt_pkrtz(cn[2], cn[3]);
      *(unsigned long long*)&Cbuf[(kb_w * 64 + lane_w) * 8 + j0] = v.u;
    }
    __syncthreads();  // c_{t+1} visible; Gbuf reads done
    bm = bm_n;
  }

  // backward cell at t=63, c0=0: h_back = (1-sig(pre_u))*tanh(pre_g)
  {
    half8_t bbk = *(const half8_t*)
        (msgbF + (size_t)(b * 32 + nt) * 256 + (lane & 31) * 8);
    half8_t au_f = *(const half8_t*)&wbfrag[(size_t)((og * 2 + 0) * 512) + lane * 8];
    half8_t ag_f = *(const half8_t*)&wbfrag[(size_t)((og * 2 + 1) * 512) + lane * 8];
    float4_t au = __builtin_amdgcn_mfma_f32_16x16x32_f16(au_f, bbk, zero4, 0, 0, 0);
    float4_t ag = __builtin_amdgcn_mfma_f32_16x16x32_f16(ag_f, bbk, zero4, 0, 0, 0);
#pragma unroll
    for (int r = 0; r < 4; ++r) {
      int row = og * 16 + q4 * 4 + r;
      float uu = rcp_(1.f + exp2_(au[r]));
      float gg = fmaf(-2.f, rcp_(exp2_(ag[r]) + 1.f), 1.f);
      hb_lds[row * 16 + l15] = (1.f - uu) * gg;
      hf_lds[row * 16 + l15] = cr[r];
    }
  }
  __syncthreads();

  // decoder
  if (tid < 192) {
    int i = tid >> 4, cc = tid & 15;
    const float* dwa = dec_w + (size_t)i * 512;
    const float* dwb = dwa + 256;
    float hd = dec_b[i];
    for (int e = 0; e < 128; ++e) {
      hd = fmaf(dwa[e] + dwb[e], hf_lds[e * 16 + cc], hd);
      hd = fmaf(dwa[128 + e] + dwb[128 + e], hb_lds[e * 16 + cc], hd);
    }
    hdec_lds[i * 16 + cc] = hd;
  }
  __syncthreads();
  if (tid < 192) {
    int o = tid >> 4, cc = tid & 15;
    float v = out_b[o];
#pragma unroll
    for (int i = 0; i < 12; ++i) v = fmaf(out_w[o * 12 + i], hdec_lds[i * 16 + cc], v);
    out[((size_t)(b * 12 + o)) * 512 + n0 + cc] = v;
  }
}

extern "C" void kernel_launch(void* const* d_in, const int* in_sizes, int n_in,
                              void* d_out, int out_size, void* d_ws, size_t ws_size,
                              hipStream_t stream) {
  (void)in_sizes; (void)n_in; (void)out_size; (void)ws_size;
  const float* x     = (const float*)d_in[0];
  const float* adj   = (const float*)d_in[1];
  const float* Wf    = (const float*)d_in[2];
  const float* Uf    = (const float*)d_in[3];
  const float* bf    = (const float*)d_in[4];
  const float* E1f   = (const float*)d_in[5];
  const float* E2f   = (const float*)d_in[6];
  const float* Wb    = (const float*)d_in[7];
  const float* bb    = (const float*)d_in[9];
  const float* E1b   = (const float*)d_in[10];
  const float* E2b   = (const float*)d_in[11];
  const float* dec_w = (const float*)d_in[12];
  const float* dec_b = (const float*)d_in[13];
  const float* out_w = (const float*)d_in[14];
  const float* out_b = (const float*)d_in[15];

  _Float16* h      = (_Float16*)d_ws;
  _Float16* adjT   = h;                        //   262144
  _Float16* AfT    = h + 262144;               //   262144
  _Float16* AbT    = h + 524288;               //   262144
  _Float16* ufrag  = h + 786432;               //    61440
  _Float16* wbfrag = h + 847872;               //     8192
  _Float16* msgF   = h + 856064;               //  8388608 (frag layout)
  _Float16* msgbF  = h + 9244672;              //   131072

  prep_kernel<<<1288, 256, 0, stream>>>(E1f, E2f, E1b, E2b, adj, Wf, Uf, bf,
                                        Wb, bb, adjT, AfT, AbT, ufrag, wbfrag);
  msg_kernel<<<512, 256, 0, stream>>>(x, adjT, AfT, AbT, msgF, msgbF);
  rec_kernel<<<512, 512, 0, stream>>>(msgF, msgbF, ufrag, wbfrag,
                                      dec_w, dec_b, out_w, out_b, (float*)d_out);
}